// Round 8
// baseline (532.159 us; speedup 1.0000x reference)
//
#include <hip/hip_runtime.h>
#include <math.h>

#define N_NODES 50000
#define N_EDGES 800000
#define DIM 128
#define EB 64        // edges/nodes per block in the MFMA kernels
#define SCAN_B 196   // ceil(N_NODES/256)
#define BN_B 256     // bn_stats blocks
#define HIST_B 3125  // N_EDGES/256
#define ECOPY_B 1563 // ceil(2*N_EDGES/4/256)
#define PREP_B 385   // ceil(98432/256)
#define APPLY_B 6250 // N_NODES*DIM/4/256
#define MIZ_B 6250   // N_NODES*DIM/4/256

typedef __attribute__((ext_vector_type(8))) short short8v;  // 8 bf16 = 4 VGPRs
typedef __attribute__((ext_vector_type(4))) float f32x4;

__device__ __forceinline__ float silu_f(float v) { return __fdividef(v, 1.f + __expf(-v)); }

__device__ __forceinline__ unsigned short f2bf(float f) {
  unsigned u = __float_as_uint(f);
  return (unsigned short)((u + 0x7fffu + ((u >> 16) & 1u)) >> 16);
}

// ================= K1: bn_stats + hist + ecopy + prep_weights (fused) =================
__global__ void k1_fused_kernel(const float* __restrict__ h, const int* __restrict__ e,
                                const float* __restrict__ fe_w1, const float* __restrict__ fe_w2,
                                const float* __restrict__ fh_w1, const float* __restrict__ fh_w2,
                                float* __restrict__ stats, int* __restrict__ cnt,
                                float* __restrict__ out_e, unsigned short* __restrict__ w1bf,
                                float* __restrict__ w1col, unsigned short* __restrict__ w2bf,
                                unsigned short* __restrict__ fw1bf, unsigned short* __restrict__ fw2bf) {
  __shared__ float red[256];
  const int bid = blockIdx.x;
  const int tid = threadIdx.x;

  if (bid < BN_B) {
    // ---- bn_stats ----
    const int c = tid & 127;
    const int rs = tid >> 7;
    float s = 0.f, s2 = 0.f;
    for (int row = bid * 2 + rs; row < N_NODES; row += BN_B * 2) {
      float v = h[(size_t)row * DIM + c];
      s += v;
      s2 += v * v;
    }
    red[tid] = s;
    __syncthreads();
    if (tid < 128) atomicAdd(&stats[c], red[c] + red[c + 128]);
    __syncthreads();
    red[tid] = s2;
    __syncthreads();
    if (tid < 128) atomicAdd(&stats[DIM + c], red[c] + red[c + 128]);
    return;
  }
  if (bid < BN_B + HIST_B) {
    const int i = (bid - BN_B) * 256 + tid;
    if (i < N_EDGES) atomicAdd(&cnt[e[i]], 1);
    return;
  }
  if (bid < BN_B + HIST_B + ECOPY_B) {
    const int i4 = (bid - BN_B - HIST_B) * 256 + tid;
    if (i4 < 2 * N_EDGES / 4) {
      const int4 v = ((const int4*)e)[i4];
      float4 o;
      o.x = (float)v.x;
      o.y = (float)v.y;
      o.z = (float)v.z;
      o.w = (float)v.w;
      ((float4*)out_e)[i4] = o;
    }
    return;
  }
  // ---- prep_weights ----
  int idx = (bid - BN_B - HIST_B - ECOPY_B) * 256 + tid;
  if (idx < 32768) {
    int o = idx >> 8, k = idx & 255;
    w1bf[idx] = f2bf(fe_w1[(size_t)o * 257 + k]);
    return;
  }
  idx -= 32768;
  if (idx < 128) { w1col[idx] = fe_w1[(size_t)idx * 257 + 256]; return; }
  idx -= 128;
  if (idx < 16384) { w2bf[idx] = f2bf(fe_w2[idx]); return; }
  idx -= 16384;
  if (idx < 32768) { fw1bf[idx] = f2bf(fh_w1[idx]); return; }
  idx -= 32768;
  if (idx < 16384) { fw2bf[idx] = f2bf(fh_w2[idx]); return; }
}

// ================= K2: scanA + bn_finalize (fused) =================
__global__ void k2_fused_kernel(const int* __restrict__ cnt, int* __restrict__ bsum,
                                float* __restrict__ stats, const float* __restrict__ gamma,
                                const float* __restrict__ beta) {
  __shared__ int red[256];
  const int bid = blockIdx.x;
  const int t = threadIdx.x;
  if (bid < SCAN_B) {
    const int i = bid * 256 + t;
    red[t] = (i < N_NODES) ? cnt[i] : 0;
    __syncthreads();
    for (int off = 128; off > 0; off >>= 1) {
      if (t < off) red[t] += red[t + off];
      __syncthreads();
    }
    if (t == 0) bsum[bid] = red[0];
    return;
  }
  // bn_finalize
  if (t < 128) {
    const float inv_n = 1.f / (float)N_NODES;
    float mean = stats[t] * inv_n;
    float var = stats[DIM + t] * inv_n - mean * mean;
    float s = gamma[t] * rsqrtf(var + 1e-5f);
    stats[2 * DIM + t] = s;
    stats[3 * DIM + t] = beta[t] - mean * s;
  }
}

__global__ void scanB_kernel(int* __restrict__ bsum) {
  __shared__ int s[256];
  const int t = threadIdx.x;
  const int v = (t < SCAN_B) ? bsum[t] : 0;
  s[t] = v;
  __syncthreads();
  for (int off = 1; off < 256; off <<= 1) {
    const int add = (t >= off) ? s[t - off] : 0;
    __syncthreads();
    s[t] += add;
    __syncthreads();
  }
  if (t < SCAN_B) bsum[t] = s[t] - v;  // exclusive block prefix
}

// ================= K3: scanC + bn_apply(bf16) + mi_g zero (fused) =================
__global__ void k3_fused_kernel(const int* __restrict__ cnt, const int* __restrict__ bsum,
                                int* __restrict__ cursor, const float* __restrict__ h,
                                const float* __restrict__ stats, unsigned short* __restrict__ hbf,
                                float* __restrict__ mi_g) {
  __shared__ int s[256];
  const int bid = blockIdx.x;
  const int t = threadIdx.x;
  if (bid < SCAN_B) {
    const int i = bid * 256 + t;
    const int v = (i < N_NODES) ? cnt[i] : 0;
    s[t] = v;
    __syncthreads();
    for (int off = 1; off < 256; off <<= 1) {
      const int add = (t >= off) ? s[t - off] : 0;
      __syncthreads();
      s[t] += add;
      __syncthreads();
    }
    if (i < N_NODES) cursor[i] = bsum[bid] + s[t] - v;
    return;
  }
  if (bid < SCAN_B + APPLY_B) {
    const int i4 = (bid - SCAN_B) * 256 + t;
    const int c4 = i4 & 31;
    const float4 v = ((const float4*)h)[i4];
    const float4 a = ((const float4*)(stats + 2 * DIM))[c4];
    const float4 b = ((const float4*)(stats + 3 * DIM))[c4];
    ushort4 o;
    o.x = f2bf(v.x * a.x + b.x);
    o.y = f2bf(v.y * a.y + b.y);
    o.z = f2bf(v.z * a.z + b.z);
    o.w = f2bf(v.w * a.w + b.w);
    ((ushort4*)hbf)[i4] = o;
    return;
  }
  const int i4 = (bid - SCAN_B - APPLY_B) * 256 + t;
  ((float4*)mi_g)[i4] = (float4){0.f, 0.f, 0.f, 0.f};
}

// scatter edges into sorted-by-src arrays; compute dist once here
__global__ void sort_scatter_kernel(const int* __restrict__ e, const float* __restrict__ x,
                                    int* __restrict__ cursor, int* __restrict__ srcS,
                                    int* __restrict__ dstS, float* __restrict__ distS) {
  const int i = blockIdx.x * blockDim.x + threadIdx.x;
  if (i >= N_EDGES) return;
  const int s = e[i], d = e[N_EDGES + i];
  const float dx = x[s * 3 + 0] - x[d * 3 + 0];
  const float dy = x[s * 3 + 1] - x[d * 3 + 1];
  const float dz = x[s * 3 + 2] - x[d * 3 + 2];
  const int pos = atomicAdd(&cursor[s], 1);
  srcS[pos] = s;
  dstS[pos] = d;
  distS[pos] = sqrtf(dx * dx + dy * dy + dz * dz);
}

// ================= edge MLP + gate + local segmented aggregation =================
// LDS: one 16 KB buffer with 4 lifetimes (src-half A / dst-half A / A2 / bf16 messages)
__launch_bounds__(256, 6)
__global__ void edge_mfma_kernel(const unsigned short* __restrict__ hbf,
                                 const int* __restrict__ srcS, const int* __restrict__ dstS,
                                 const float* __restrict__ distS,
                                 const unsigned short* __restrict__ w1bf, const float* __restrict__ w1col,
                                 const float* __restrict__ b1, const unsigned short* __restrict__ w2bf,
                                 const float* __restrict__ b2, const float* __restrict__ winf,
                                 const float* __restrict__ binf, float* __restrict__ mi_g) {
  __shared__ unsigned short buf[EB * 128];  // 16 KB
  __shared__ int srcs[EB];
  __shared__ int dsts[EB];
  __shared__ float dists[EB];
  __shared__ float gbuf[EB][5];
  __shared__ float gate[EB];

  const int tid = threadIdx.x;
  const int l = tid & 63, w = tid >> 6;
  const int r16 = l & 15, g = l >> 4;
  const int ebase = blockIdx.x * EB;

  if (tid < EB) {
    srcs[tid] = srcS[ebase + tid];
    dsts[tid] = dstS[ebase + tid];
    dists[tid] = distS[ebase + tid];
  }
  __syncthreads();

  const int er_s = tid >> 2, cb_s = (tid & 3) * 4;  // 4 chunks (of 8 bf16) per thread

  // ---- phase A: stage src half (k<128) ----
  {
    const unsigned short* ps = hbf + (size_t)srcs[er_s] * DIM;
#pragma unroll
    for (int j = 0; j < 4; ++j) {
      const int c = cb_s + j;
      *(int4*)&buf[er_s * 128 + ((c ^ (er_s & 7)) << 3)] = *(const int4*)(ps + c * 8);
    }
  }
  __syncthreads();

  f32x4 acc[4][2];
#pragma unroll
  for (int m_ = 0; m_ < 4; ++m_)
#pragma unroll
    for (int ni = 0; ni < 2; ++ni) acc[m_][ni] = (f32x4){0.f, 0.f, 0.f, 0.f};

#pragma unroll
  for (int kb = 0; kb < 4; ++kb) {
    short8v a[4], b[2];
#pragma unroll
    for (int m_ = 0; m_ < 4; ++m_) {
      const int er = m_ * 16 + r16;
      a[m_] = *(const short8v*)&buf[er * 128 + (((kb * 4 + g) ^ (er & 7)) << 3)];
    }
#pragma unroll
    for (int ni = 0; ni < 2; ++ni) {
      const int o = w * 32 + ni * 16 + r16;
      b[ni] = *(const short8v*)&w1bf[o * 256 + kb * 32 + g * 8];
    }
#pragma unroll
    for (int m_ = 0; m_ < 4; ++m_)
#pragma unroll
      for (int ni = 0; ni < 2; ++ni)
        acc[m_][ni] = __builtin_amdgcn_mfma_f32_16x16x32_bf16(a[m_], b[ni], acc[m_][ni], 0, 0, 0);
  }
  __syncthreads();

  // ---- phase B: stage dst half (k in [128,256)) into the same buffer ----
  {
    const unsigned short* pd = hbf + (size_t)dsts[er_s] * DIM;
#pragma unroll
    for (int j = 0; j < 4; ++j) {
      const int c = cb_s + j;
      *(int4*)&buf[er_s * 128 + ((c ^ (er_s & 7)) << 3)] = *(const int4*)(pd + c * 8);
    }
  }
  __syncthreads();

#pragma unroll
  for (int kb = 4; kb < 8; ++kb) {
    short8v a[4], b[2];
#pragma unroll
    for (int m_ = 0; m_ < 4; ++m_) {
      const int er = m_ * 16 + r16;
      a[m_] = *(const short8v*)&buf[er * 128 + ((((kb - 4) * 4 + g) ^ (er & 7)) << 3)];
    }
#pragma unroll
    for (int ni = 0; ni < 2; ++ni) {
      const int o = w * 32 + ni * 16 + r16;
      b[ni] = *(const short8v*)&w1bf[o * 256 + kb * 32 + g * 8];
    }
#pragma unroll
    for (int m_ = 0; m_ < 4; ++m_)
#pragma unroll
      for (int ni = 0; ni < 2; ++ni)
        acc[m_][ni] = __builtin_amdgcn_mfma_f32_16x16x32_bf16(a[m_], b[ni], acc[m_][ni], 0, 0, 0);
  }
  __syncthreads();

  // ---- tail k=256 (dist col) + bias + SiLU -> A2 (same buffer, bf16 swizzled) ----
  {
    const int o0 = w * 32 + r16, o1 = o0 + 16;
    const float wc0 = w1col[o0], wc1 = w1col[o1];
    const float bb0 = b1[o0], bb1 = b1[o1];
#pragma unroll
    for (int m_ = 0; m_ < 4; ++m_)
#pragma unroll
      for (int r = 0; r < 4; ++r) {
        const int er = m_ * 16 + g * 4 + r;
        const float dd = dists[er];
        buf[er * 128 + (o0 ^ ((er & 7) << 3))] = f2bf(silu_f(acc[m_][0][r] + dd * wc0 + bb0));
        buf[er * 128 + (o1 ^ ((er & 7) << 3))] = f2bf(silu_f(acc[m_][1][r] + dd * wc1 + bb1));
      }
  }
  __syncthreads();

  // ---- GEMM2: K = 128 ----
  f32x4 acc2[4][2];
#pragma unroll
  for (int m_ = 0; m_ < 4; ++m_)
#pragma unroll
    for (int ni = 0; ni < 2; ++ni) acc2[m_][ni] = (f32x4){0.f, 0.f, 0.f, 0.f};

#pragma unroll
  for (int kb = 0; kb < 4; ++kb) {
    short8v a[4], b[2];
    const int k0 = kb * 32 + g * 8;
#pragma unroll
    for (int m_ = 0; m_ < 4; ++m_) {
      const int er = m_ * 16 + r16;
      a[m_] = *(const short8v*)&buf[er * 128 + (k0 ^ ((er & 7) << 3))];
    }
#pragma unroll
    for (int ni = 0; ni < 2; ++ni) {
      const int o = w * 32 + ni * 16 + r16;
      b[ni] = *(const short8v*)&w2bf[o * 128 + k0];
    }
#pragma unroll
    for (int m_ = 0; m_ < 4; ++m_)
#pragma unroll
      for (int ni = 0; ni < 2; ++ni)
        acc2[m_][ni] = __builtin_amdgcn_mfma_f32_16x16x32_bf16(a[m_], b[ni], acc2[m_][ni], 0, 0, 0);
  }

  // ---- bias + SiLU in place; gate partials ----
  float pv[16];
  {
    const int o0 = w * 32 + r16, o1 = o0 + 16;
    const float b20 = b2[o0], b21 = b2[o1];
    const float wf0 = winf[o0], wf1 = winf[o1];
#pragma unroll
    for (int m_ = 0; m_ < 4; ++m_)
#pragma unroll
      for (int r = 0; r < 4; ++r) {
        const float v0 = silu_f(acc2[m_][0][r] + b20);
        const float v1 = silu_f(acc2[m_][1][r] + b21);
        acc2[m_][0][r] = v0;
        acc2[m_][1][r] = v1;
        pv[m_ * 4 + r] = v0 * wf0 + v1 * wf1;
      }
  }

  // ---- reduce-scatter over 16 lanes: 15 shfl ----
  {
    const bool s0 = r16 & 1;
#pragma unroll
    for (int j = 0; j < 8; ++j) {
      const float lo = pv[2 * j], hi = pv[2 * j + 1];
      const float other = __shfl_xor(s0 ? lo : hi, 1, 64);
      pv[j] = (s0 ? hi : lo) + other;
    }
    const bool s1 = r16 & 2;
#pragma unroll
    for (int j = 0; j < 4; ++j) {
      const float lo = pv[2 * j], hi = pv[2 * j + 1];
      const float other = __shfl_xor(s1 ? lo : hi, 2, 64);
      pv[j] = (s1 ? hi : lo) + other;
    }
    const bool s2 = r16 & 4;
#pragma unroll
    for (int j = 0; j < 2; ++j) {
      const float lo = pv[2 * j], hi = pv[2 * j + 1];
      const float other = __shfl_xor(s2 ? lo : hi, 4, 64);
      pv[j] = (s2 ? hi : lo) + other;
    }
    const bool s3 = r16 & 8;
    {
      const float lo = pv[0], hi = pv[1];
      const float other = __shfl_xor(s3 ? lo : hi, 8, 64);
      pv[0] = (s3 ? hi : lo) + other;
    }
    const int er = (r16 >> 2) * 16 + g * 4 + (r16 & 3);
    gbuf[er][w] = pv[0];
  }
  __syncthreads();
  if (tid < EB) {
    const float s = gbuf[tid][0] + gbuf[tid][1] + gbuf[tid][2] + gbuf[tid][3] + binf[0];
    gate[tid] = __fdividef(1.f, 1.f + __expf(-s));
  }
  __syncthreads();

  // ---- gated messages -> bf16 tile (same buffer; A2 reads all completed) ----
  {
    const int o0 = w * 32 + r16, o1 = o0 + 16;
#pragma unroll
    for (int m_ = 0; m_ < 4; ++m_)
#pragma unroll
      for (int r = 0; r < 4; ++r) {
        const int er = m_ * 16 + g * 4 + r;
        const float gg = gate[er];
        buf[er * 128 + (o0 ^ ((er & 7) << 3))] = f2bf(acc2[m_][0][r] * gg);
        buf[er * 128 + (o1 ^ ((er & 7) << 3))] = f2bf(acc2[m_][1][r] * gg);
      }
  }
  __syncthreads();

  // ---- segmented column reduction over sorted srcs; one atomic per run ----
  {
    const int c = tid & 127;
    const int r0 = (tid >> 7) * 32;
    int cur = srcs[r0];
    float a = 0.f;
    for (int row = r0; row < r0 + 32; ++row) {
      const int s = srcs[row];  // wave-uniform
      if (s != cur) {
        atomicAdd(&mi_g[(size_t)cur * DIM + c], a);
        a = 0.f;
        cur = s;
      }
      a += __uint_as_float((unsigned)buf[row * 128 + (c ^ ((row & 7) << 3))] << 16);
    }
    atomicAdd(&mi_g[(size_t)cur * DIM + c], a);
  }
}

// ================= node MLP (MFMA, split-K staging) + residual =================
__launch_bounds__(256, 6)
__global__ void node_mfma_kernel(const unsigned short* __restrict__ hbf,
                                 const float* __restrict__ mi_g,
                                 const float* __restrict__ h, const float* __restrict__ stats,
                                 const unsigned short* __restrict__ fw1, const float* __restrict__ fb1,
                                 const unsigned short* __restrict__ fw2, const float* __restrict__ fb2,
                                 float* __restrict__ out) {
  __shared__ unsigned short buf[EB * 128];  // 16 KB

  const int tid = threadIdx.x;
  const int l = tid & 63, w = tid >> 6;
  const int r16 = l & 15, g = l >> 4;
  const int nbase = blockIdx.x * EB;

  const int er_s = tid >> 2, cb_s = (tid & 3) * 4;
  int nstg = nbase + er_s;
  if (nstg >= N_NODES) nstg = N_NODES - 1;

  // ---- phase A: h half ----
  {
    const unsigned short* ps = hbf + (size_t)nstg * DIM;
#pragma unroll
    for (int j = 0; j < 4; ++j) {
      const int c = cb_s + j;
      *(int4*)&buf[er_s * 128 + ((c ^ (er_s & 7)) << 3)] = *(const int4*)(ps + c * 8);
    }
  }
  __syncthreads();

  f32x4 acc[4][2];
#pragma unroll
  for (int m_ = 0; m_ < 4; ++m_)
#pragma unroll
    for (int ni = 0; ni < 2; ++ni) acc[m_][ni] = (f32x4){0.f, 0.f, 0.f, 0.f};

#pragma unroll
  for (int kb = 0; kb < 4; ++kb) {
    short8v a[4], b[2];
#pragma unroll
    for (int m_ = 0; m_ < 4; ++m_) {
      const int er = m_ * 16 + r16;
      a[m_] = *(const short8v*)&buf[er * 128 + (((kb * 4 + g) ^ (er & 7)) << 3)];
    }
#pragma unroll
    for (int ni = 0; ni < 2; ++ni) {
      const int o = w * 32 + ni * 16 + r16;
      b[ni] = *(const short8v*)&fw1[o * 256 + kb * 32 + g * 8];
    }
#pragma unroll
    for (int m_ = 0; m_ < 4; ++m_)
#pragma unroll
      for (int ni = 0; ni < 2; ++ni)
        acc[m_][ni] = __builtin_amdgcn_mfma_f32_16x16x32_bf16(a[m_], b[ni], acc[m_][ni], 0, 0, 0);
  }
  __syncthreads();

  // ---- phase B: m_i half (fp32 -> bf16 on the fly) ----
  {
    const float* pm = mi_g + (size_t)nstg * DIM;
#pragma unroll
    for (int j = 0; j < 4; ++j) {
      const int c = cb_s + j;
      const float4 f0 = *(const float4*)(pm + c * 8);
      const float4 f1 = *(const float4*)(pm + c * 8 + 4);
      int4 v;
      v.x = (int)f2bf(f0.x) | ((int)f2bf(f0.y) << 16);
      v.y = (int)f2bf(f0.z) | ((int)f2bf(f0.w) << 16);
      v.z = (int)f2bf(f1.x) | ((int)f2bf(f1.y) << 16);
      v.w = (int)f2bf(f1.z) | ((int)f2bf(f1.w) << 16);
      *(int4*)&buf[er_s * 128 + ((c ^ (er_s & 7)) << 3)] = v;
    }
  }
  __syncthreads();

#pragma unroll
  for (int kb = 4; kb < 8; ++kb) {
    short8v a[4], b[2];
#pragma unroll
    for (int m_ = 0; m_ < 4; ++m_) {
      const int er = m_ * 16 + r16;
      a[m_] = *(const short8v*)&buf[er * 128 + ((((kb - 4) * 4 + g) ^ (er & 7)) << 3)];
    }
#pragma unroll
    for (int ni = 0; ni < 2; ++ni) {
      const int o = w * 32 + ni * 16 + r16;
      b[ni] = *(const short8v*)&fw1[o * 256 + kb * 32 + g * 8];
    }
#pragma unroll
    for (int m_ = 0; m_ < 4; ++m_)
#pragma unroll
      for (int ni = 0; ni < 2; ++ni)
        acc[m_][ni] = __builtin_amdgcn_mfma_f32_16x16x32_bf16(a[m_], b[ni], acc[m_][ni], 0, 0, 0);
  }
  __syncthreads();

  // ---- bias + SiLU -> A2 (same buffer) ----
  {
    const int o0 = w * 32 + r16, o1 = o0 + 16;
    const float bb0 = fb1[o0], bb1 = fb1[o1];
#pragma unroll
    for (int m_ = 0; m_ < 4; ++m_)
#pragma unroll
      for (int r = 0; r < 4; ++r) {
        const int er = m_ * 16 + g * 4 + r;
        buf[er * 128 + (o0 ^ ((er & 7) << 3))] = f2bf(silu_f(acc[m_][0][r] + bb0));
        buf[er * 128 + (o1 ^ ((er & 7) << 3))] = f2bf(silu_f(acc[m_][1][r] + bb1));
      }
  }
  __syncthreads();

  f32x4 acc2[4][2];
#pragma unroll
  for (int m_ = 0; m_ < 4; ++m_)
#pragma unroll
    for (int ni = 0; ni < 2; ++ni) acc2[m_][ni] = (f32x4){0.f, 0.f, 0.f, 0.f};

#pragma unroll
  for (int kb = 0; kb < 4; ++kb) {
    short8v a[4], b[2];
    const int k0 = kb * 32 + g * 8;
#pragma unroll
    for (int m_ = 0; m_ < 4; ++m_) {
      const int er = m_ * 16 + r16;
      a[m_] = *(const short8v*)&buf[er * 128 + (k0 ^ ((er & 7) << 3))];
    }
#pragma unroll
    for (int ni = 0; ni < 2; ++ni) {
      const int o = w * 32 + ni * 16 + r16;
      b[ni] = *(const short8v*)&fw2[o * 128 + k0];
    }
#pragma unroll
    for (int m_ = 0; m_ < 4; ++m_)
#pragma unroll
      for (int ni = 0; ni < 2; ++ni)
        acc2[m_][ni] = __builtin_amdgcn_mfma_f32_16x16x32_bf16(a[m_], b[ni], acc2[m_][ni], 0, 0, 0);
  }

  // epilogue: out = BN(h) + update
#pragma unroll
  for (int ni = 0; ni < 2; ++ni) {
    const int o = w * 32 + ni * 16 + r16;
    const float bb = fb2[o];
    const float sc = stats[2 * DIM + o];
    const float sh = stats[3 * DIM + o];
#pragma unroll
    for (int m_ = 0; m_ < 4; ++m_)
#pragma unroll
      for (int r = 0; r < 4; ++r) {
        const int n = nbase + m_ * 16 + g * 4 + r;
        if (n < N_NODES) {
          const float hv = h[(size_t)n * DIM + o];
          out[(size_t)n * DIM + o] = hv * sc + sh + acc2[m_][ni][r] + bb;
        }
      }
  }
}

extern "C" void kernel_launch(void* const* d_in, const int* in_sizes, int n_in, void* d_out,
                              int out_size, void* d_ws, size_t ws_size, hipStream_t stream) {
  const float* h = (const float*)d_in[0];
  const float* x = (const float*)d_in[1];
  const int* e = (const int*)d_in[2];
  const float* bn_gamma = (const float*)d_in[3];
  const float* bn_beta = (const float*)d_in[4];
  const float* fe_w1 = (const float*)d_in[5];
  const float* fe_b1 = (const float*)d_in[6];
  const float* fe_w2 = (const float*)d_in[7];
  const float* fe_b2 = (const float*)d_in[8];
  const float* finf_w = (const float*)d_in[9];
  const float* finf_b = (const float*)d_in[10];
  const float* fh_w1 = (const float*)d_in[11];
  const float* fh_b1 = (const float*)d_in[12];
  const float* fh_w2 = (const float*)d_in[13];
  const float* fh_b2 = (const float*)d_in[14];

  char* wp = (char*)d_ws;
  auto alloc = [&](size_t bytes) -> char* {
    char* p = wp;
    wp += (bytes + 255) & ~(size_t)255;
    return p;
  };
  float* stats = (float*)alloc(512 * sizeof(float));        // 2048 B (256-aligned)
  int* cnt = (int*)alloc((size_t)N_NODES * 4);              // adjacent to stats for one memset
  unsigned short* hbf = (unsigned short*)alloc((size_t)N_NODES * DIM * 2);
  unsigned short* w1bf = (unsigned short*)alloc(128 * 256 * 2);
  float* w1col = (float*)alloc(128 * 4);
  unsigned short* w2bf = (unsigned short*)alloc(128 * 128 * 2);
  unsigned short* fw1bf = (unsigned short*)alloc(128 * 256 * 2);
  unsigned short* fw2bf = (unsigned short*)alloc(128 * 128 * 2);
  int* cursor = (int*)alloc((size_t)N_NODES * 4);
  int* bsum = (int*)alloc((size_t)SCAN_B * 4);
  int* srcS = (int*)alloc((size_t)N_EDGES * 4);
  int* dstS = (int*)alloc((size_t)N_EDGES * 4);
  float* distS = (float*)alloc((size_t)N_EDGES * 4);
  float* mi_g = (float*)alloc((size_t)N_NODES * DIM * 4);

  float* out = (float*)d_out;
  float* out_e = out + (size_t)N_NODES * DIM;

  // one memset covers stats (2048 B) + cnt (200000 B), laid out contiguously
  hipMemsetAsync(stats, 0, 2048 + (size_t)N_NODES * 4, stream);

  k1_fused_kernel<<<BN_B + HIST_B + ECOPY_B + PREP_B, 256, 0, stream>>>(
      h, e, fe_w1, fe_w2, fh_w1, fh_w2, stats, cnt, out_e, w1bf, w1col, w2bf, fw1bf, fw2bf);
  k2_fused_kernel<<<SCAN_B + 1, 256, 0, stream>>>(cnt, bsum, stats, bn_gamma, bn_beta);
  scanB_kernel<<<1, 256, 0, stream>>>(bsum);
  k3_fused_kernel<<<SCAN_B + APPLY_B + MIZ_B, 256, 0, stream>>>(cnt, bsum, cursor, h, stats, hbf,
                                                                mi_g);
  sort_scatter_kernel<<<(N_EDGES + 255) / 256, 256, 0, stream>>>(e, x, cursor, srcS, dstS, distS);
  edge_mfma_kernel<<<N_EDGES / EB, 256, 0, stream>>>(hbf, srcS, dstS, distS, w1bf, w1col, fe_b1,
                                                     w2bf, fe_b2, finf_w, finf_b, mi_g);
  node_mfma_kernel<<<(N_NODES + EB - 1) / EB, 256, 0, stream>>>(hbf, mi_g, h, stats, fw1bf, fh_b1,
                                                                fw2bf, fh_b2, out);
}

// Round 9
// 478.489 us; speedup vs baseline: 1.1122x; 1.1122x over previous
//
#include <hip/hip_runtime.h>
#include <math.h>

#define N_NODES 50000
#define N_EDGES 800000
#define DIM 128
#define EB 64        // edges/nodes per block in the MFMA kernels
#define SCAN_B 196   // ceil(N_NODES/256)
#define BN_B 256     // bn_stats blocks
#define HIST_B 3125  // N_EDGES/256
#define ECOPY_B 1563 // ceil(2*N_EDGES/4/256)
#define PREP_B 385   // ceil(98432/256)
#define APPLY_B 6250 // N_NODES*DIM/4/256
#define MIZ_B 6250   // N_NODES*DIM/4/256

typedef __attribute__((ext_vector_type(8))) short short8v;  // 8 bf16 = 4 VGPRs
typedef __attribute__((ext_vector_type(4))) float f32x4;

__device__ __forceinline__ float silu_f(float v) { return __fdividef(v, 1.f + __expf(-v)); }

__device__ __forceinline__ unsigned short f2bf(float f) {
  unsigned u = __float_as_uint(f);
  return (unsigned short)((u + 0x7fffu + ((u >> 16) & 1u)) >> 16);
}

// ================= K1: bn_stats + hist + ecopy + prep_weights (fused) =================
__global__ void k1_fused_kernel(const float* __restrict__ h, const int* __restrict__ e,
                                const float* __restrict__ fe_w1, const float* __restrict__ fe_w2,
                                const float* __restrict__ fh_w1, const float* __restrict__ fh_w2,
                                float* __restrict__ stats, int* __restrict__ cnt,
                                float* __restrict__ out_e, unsigned short* __restrict__ w1bf,
                                float* __restrict__ w1col, unsigned short* __restrict__ w2bf,
                                unsigned short* __restrict__ fw1bf, unsigned short* __restrict__ fw2bf) {
  __shared__ float red[256];
  const int bid = blockIdx.x;
  const int tid = threadIdx.x;

  if (bid < BN_B) {
    // ---- bn_stats ----
    const int c = tid & 127;
    const int rs = tid >> 7;
    float s = 0.f, s2 = 0.f;
    for (int row = bid * 2 + rs; row < N_NODES; row += BN_B * 2) {
      float v = h[(size_t)row * DIM + c];
      s += v;
      s2 += v * v;
    }
    red[tid] = s;
    __syncthreads();
    if (tid < 128) atomicAdd(&stats[c], red[c] + red[c + 128]);
    __syncthreads();
    red[tid] = s2;
    __syncthreads();
    if (tid < 128) atomicAdd(&stats[DIM + c], red[c] + red[c + 128]);
    return;
  }
  if (bid < BN_B + HIST_B) {
    const int i = (bid - BN_B) * 256 + tid;
    if (i < N_EDGES) atomicAdd(&cnt[e[i]], 1);
    return;
  }
  if (bid < BN_B + HIST_B + ECOPY_B) {
    const int i4 = (bid - BN_B - HIST_B) * 256 + tid;
    if (i4 < 2 * N_EDGES / 4) {
      const int4 v = ((const int4*)e)[i4];
      float4 o;
      o.x = (float)v.x;
      o.y = (float)v.y;
      o.z = (float)v.z;
      o.w = (float)v.w;
      ((float4*)out_e)[i4] = o;
    }
    return;
  }
  // ---- prep_weights ----
  int idx = (bid - BN_B - HIST_B - ECOPY_B) * 256 + tid;
  if (idx < 32768) {
    int o = idx >> 8, k = idx & 255;
    w1bf[idx] = f2bf(fe_w1[(size_t)o * 257 + k]);
    return;
  }
  idx -= 32768;
  if (idx < 128) { w1col[idx] = fe_w1[(size_t)idx * 257 + 256]; return; }
  idx -= 128;
  if (idx < 16384) { w2bf[idx] = f2bf(fe_w2[idx]); return; }
  idx -= 16384;
  if (idx < 32768) { fw1bf[idx] = f2bf(fh_w1[idx]); return; }
  idx -= 32768;
  if (idx < 16384) { fw2bf[idx] = f2bf(fh_w2[idx]); return; }
}

// ================= K2: scanA + bn_finalize (fused) =================
__global__ void k2_fused_kernel(const int* __restrict__ cnt, int* __restrict__ bsum,
                                float* __restrict__ stats, const float* __restrict__ gamma,
                                const float* __restrict__ beta) {
  __shared__ int red[256];
  const int bid = blockIdx.x;
  const int t = threadIdx.x;
  if (bid < SCAN_B) {
    const int i = bid * 256 + t;
    red[t] = (i < N_NODES) ? cnt[i] : 0;
    __syncthreads();
    for (int off = 128; off > 0; off >>= 1) {
      if (t < off) red[t] += red[t + off];
      __syncthreads();
    }
    if (t == 0) bsum[bid] = red[0];
    return;
  }
  // bn_finalize
  if (t < 128) {
    const float inv_n = 1.f / (float)N_NODES;
    float mean = stats[t] * inv_n;
    float var = stats[DIM + t] * inv_n - mean * mean;
    float s = gamma[t] * rsqrtf(var + 1e-5f);
    stats[2 * DIM + t] = s;
    stats[3 * DIM + t] = beta[t] - mean * s;
  }
}

__global__ void scanB_kernel(int* __restrict__ bsum) {
  __shared__ int s[256];
  const int t = threadIdx.x;
  const int v = (t < SCAN_B) ? bsum[t] : 0;
  s[t] = v;
  __syncthreads();
  for (int off = 1; off < 256; off <<= 1) {
    const int add = (t >= off) ? s[t - off] : 0;
    __syncthreads();
    s[t] += add;
    __syncthreads();
  }
  if (t < SCAN_B) bsum[t] = s[t] - v;  // exclusive block prefix
}

// ================= K3: scanC + bn_apply(bf16) + mi_g zero (fused) =================
__global__ void k3_fused_kernel(const int* __restrict__ cnt, const int* __restrict__ bsum,
                                int* __restrict__ cursor, const float* __restrict__ h,
                                const float* __restrict__ stats, unsigned short* __restrict__ hbf,
                                float* __restrict__ mi_g) {
  __shared__ int s[256];
  const int bid = blockIdx.x;
  const int t = threadIdx.x;
  if (bid < SCAN_B) {
    const int i = bid * 256 + t;
    const int v = (i < N_NODES) ? cnt[i] : 0;
    s[t] = v;
    __syncthreads();
    for (int off = 1; off < 256; off <<= 1) {
      const int add = (t >= off) ? s[t - off] : 0;
      __syncthreads();
      s[t] += add;
      __syncthreads();
    }
    if (i < N_NODES) cursor[i] = bsum[bid] + s[t] - v;
    return;
  }
  if (bid < SCAN_B + APPLY_B) {
    const int i4 = (bid - SCAN_B) * 256 + t;
    const int c4 = i4 & 31;
    const float4 v = ((const float4*)h)[i4];
    const float4 a = ((const float4*)(stats + 2 * DIM))[c4];
    const float4 b = ((const float4*)(stats + 3 * DIM))[c4];
    ushort4 o;
    o.x = f2bf(v.x * a.x + b.x);
    o.y = f2bf(v.y * a.y + b.y);
    o.z = f2bf(v.z * a.z + b.z);
    o.w = f2bf(v.w * a.w + b.w);
    ((ushort4*)hbf)[i4] = o;
    return;
  }
  const int i4 = (bid - SCAN_B - APPLY_B) * 256 + t;
  ((float4*)mi_g)[i4] = (float4){0.f, 0.f, 0.f, 0.f};
}

// scatter edges into sorted-by-src arrays; compute dist once here
__global__ void sort_scatter_kernel(const int* __restrict__ e, const float* __restrict__ x,
                                    int* __restrict__ cursor, int* __restrict__ srcS,
                                    int* __restrict__ dstS, float* __restrict__ distS) {
  const int i = blockIdx.x * blockDim.x + threadIdx.x;
  if (i >= N_EDGES) return;
  const int s = e[i], d = e[N_EDGES + i];
  const float dx = x[s * 3 + 0] - x[d * 3 + 0];
  const float dy = x[s * 3 + 1] - x[d * 3 + 1];
  const float dz = x[s * 3 + 2] - x[d * 3 + 2];
  const int pos = atomicAdd(&cursor[s], 1);
  srcS[pos] = s;
  dstS[pos] = d;
  distS[pos] = sqrtf(dx * dx + dy * dy + dz * dz);
}

// ================= edge MLP + gate + local segmented aggregation =================
// Round-4 structure (proven 246 us) + bijective XCD-chunked block swizzle.
// LDS: Abuf 32 KB, three lifetimes (GEMM1 A / A2 in lower half / fp32 message tile)
__launch_bounds__(256, 4)
__global__ void edge_mfma_kernel(const unsigned short* __restrict__ hbf,
                                 const int* __restrict__ srcS, const int* __restrict__ dstS,
                                 const float* __restrict__ distS,
                                 const unsigned short* __restrict__ w1bf, const float* __restrict__ w1col,
                                 const float* __restrict__ b1, const unsigned short* __restrict__ w2bf,
                                 const float* __restrict__ b2, const float* __restrict__ winf,
                                 const float* __restrict__ binf, float* __restrict__ mi_g) {
  __shared__ unsigned short Abuf[EB * 256];  // 32 KB
  __shared__ int srcs[EB];
  __shared__ int dsts[EB];
  __shared__ float dists[EB];
  __shared__ float gbuf[EB][5];
  __shared__ float gate[EB];

  unsigned short* A2 = Abuf;   // lower 16 KB, after GEMM1 reads complete
  float* Mf = (float*)Abuf;    // full 32 KB fp32[64][128], after GEMM2 reads complete

  const int tid = threadIdx.x;
  const int l = tid & 63, w = tid >> 6;
  const int r16 = l & 15, g = l >> 4;

  // Bijective XCD-chunked swizzle (nwg = 12500, 8 XCDs, r = 4):
  // consecutive sorted-edge blocks stay on one XCD for mi_g / src-row L2 locality.
  const int nwg = N_EDGES / EB;
  const int q = nwg >> 3, r = nwg & 7;
  const int xcd = blockIdx.x & 7;
  const int idx = blockIdx.x >> 3;
  const int bid = (xcd < r ? xcd * (q + 1) : r * (q + 1) + (xcd - r) * q) + idx;
  const int ebase = bid * EB;

  if (tid < EB) {
    srcs[tid] = srcS[ebase + tid];
    dsts[tid] = dstS[ebase + tid];
    dists[tid] = distS[ebase + tid];
  }
  __syncthreads();

  // stage A[e][k] bf16: k<128 = h[src], 128..255 = h[dst]; 16B chunks XOR-swizzled
  {
    const int er = tid >> 2, cb = (tid & 3) * 8;
    const unsigned short* ps = hbf + (size_t)srcs[er] * DIM;
    const unsigned short* pd = hbf + (size_t)dsts[er] * DIM;
#pragma unroll
    for (int j = 0; j < 8; ++j) {
      const int c = cb + j;  // chunk 0..31 (8 elems each)
      const int4 v = (c < 16) ? *(const int4*)(ps + c * 8) : *(const int4*)(pd + (c - 16) * 8);
      *(int4*)&Abuf[er * 256 + ((c ^ (er & 7)) << 3)] = v;
    }
  }
  __syncthreads();

  // ---- GEMM1: D[64 e][128 o] = A[64][256] x W1^T, K=256 via MFMA ----
  f32x4 acc[4][2];
#pragma unroll
  for (int m_ = 0; m_ < 4; ++m_)
#pragma unroll
    for (int ni = 0; ni < 2; ++ni) acc[m_][ni] = (f32x4){0.f, 0.f, 0.f, 0.f};

  for (int kb = 0; kb < 8; ++kb) {
    short8v a[4], b[2];
#pragma unroll
    for (int m_ = 0; m_ < 4; ++m_) {
      const int er = m_ * 16 + r16;
      const int chunk = kb * 4 + g;
      a[m_] = *(const short8v*)&Abuf[er * 256 + ((chunk ^ (er & 7)) << 3)];
    }
#pragma unroll
    for (int ni = 0; ni < 2; ++ni) {
      const int o = w * 32 + ni * 16 + r16;
      b[ni] = *(const short8v*)&w1bf[o * 256 + kb * 32 + g * 8];
    }
#pragma unroll
    for (int m_ = 0; m_ < 4; ++m_)
#pragma unroll
      for (int ni = 0; ni < 2; ++ni)
        acc[m_][ni] = __builtin_amdgcn_mfma_f32_16x16x32_bf16(a[m_], b[ni], acc[m_][ni], 0, 0, 0);
  }
  __syncthreads();  // all Abuf reads done; A2 region may be overwritten

  // tail k=256 (dist column, fp32 rank-1) + bias + SiLU -> A2 (swizzled bf16)
  {
    const int o0 = w * 32 + r16, o1 = o0 + 16;
    const float wc0 = w1col[o0], wc1 = w1col[o1];
    const float bb0 = b1[o0], bb1 = b1[o1];
#pragma unroll
    for (int m_ = 0; m_ < 4; ++m_)
#pragma unroll
      for (int r_ = 0; r_ < 4; ++r_) {
        const int er = m_ * 16 + g * 4 + r_;
        const float dd = dists[er];
        const float v0 = silu_f(acc[m_][0][r_] + dd * wc0 + bb0);
        const float v1 = silu_f(acc[m_][1][r_] + dd * wc1 + bb1);
        A2[er * 128 + (o0 ^ ((er & 7) << 3))] = f2bf(v0);
        A2[er * 128 + (o1 ^ ((er & 7) << 3))] = f2bf(v1);
      }
  }
  __syncthreads();

  // ---- GEMM2: K = 128 ----
  f32x4 acc2[4][2];
#pragma unroll
  for (int m_ = 0; m_ < 4; ++m_)
#pragma unroll
    for (int ni = 0; ni < 2; ++ni) acc2[m_][ni] = (f32x4){0.f, 0.f, 0.f, 0.f};

  for (int kb = 0; kb < 4; ++kb) {
    short8v a[4], b[2];
    const int k0 = kb * 32 + g * 8;
#pragma unroll
    for (int m_ = 0; m_ < 4; ++m_) {
      const int er = m_ * 16 + r16;
      a[m_] = *(const short8v*)&A2[er * 128 + (k0 ^ ((er & 7) << 3))];
    }
#pragma unroll
    for (int ni = 0; ni < 2; ++ni) {
      const int o = w * 32 + ni * 16 + r16;
      b[ni] = *(const short8v*)&w2bf[o * 128 + k0];
    }
#pragma unroll
    for (int m_ = 0; m_ < 4; ++m_)
#pragma unroll
      for (int ni = 0; ni < 2; ++ni)
        acc2[m_][ni] = __builtin_amdgcn_mfma_f32_16x16x32_bf16(a[m_], b[ni], acc2[m_][ni], 0, 0, 0);
  }

  // ---- bias + SiLU in place; gate partials ----
  float pv[16];
  {
    const int o0 = w * 32 + r16, o1 = o0 + 16;
    const float b20 = b2[o0], b21 = b2[o1];
    const float wf0 = winf[o0], wf1 = winf[o1];
#pragma unroll
    for (int m_ = 0; m_ < 4; ++m_)
#pragma unroll
      for (int r_ = 0; r_ < 4; ++r_) {
        const float v0 = silu_f(acc2[m_][0][r_] + b20);
        const float v1 = silu_f(acc2[m_][1][r_] + b21);
        acc2[m_][0][r_] = v0;
        acc2[m_][1][r_] = v1;
        pv[m_ * 4 + r_] = v0 * wf0 + v1 * wf1;
      }
  }

  // ---- reduce-scatter over the 16 lanes: 15 shfl ----
  {
    const bool s0 = r16 & 1;
#pragma unroll
    for (int j = 0; j < 8; ++j) {
      const float lo = pv[2 * j], hi = pv[2 * j + 1];
      const float other = __shfl_xor(s0 ? lo : hi, 1, 64);
      pv[j] = (s0 ? hi : lo) + other;
    }
    const bool s1 = r16 & 2;
#pragma unroll
    for (int j = 0; j < 4; ++j) {
      const float lo = pv[2 * j], hi = pv[2 * j + 1];
      const float other = __shfl_xor(s1 ? lo : hi, 2, 64);
      pv[j] = (s1 ? hi : lo) + other;
    }
    const bool s2 = r16 & 4;
#pragma unroll
    for (int j = 0; j < 2; ++j) {
      const float lo = pv[2 * j], hi = pv[2 * j + 1];
      const float other = __shfl_xor(s2 ? lo : hi, 4, 64);
      pv[j] = (s2 ? hi : lo) + other;
    }
    const bool s3 = r16 & 8;
    {
      const float lo = pv[0], hi = pv[1];
      const float other = __shfl_xor(s3 ? lo : hi, 8, 64);
      pv[0] = (s3 ? hi : lo) + other;
    }
    const int er = (r16 >> 2) * 16 + g * 4 + (r16 & 3);
    gbuf[er][w] = pv[0];
  }
  __syncthreads();  // also guarantees all GEMM2 A2-reads are done
  if (tid < EB) {
    const float s = gbuf[tid][0] + gbuf[tid][1] + gbuf[tid][2] + gbuf[tid][3] + binf[0];
    gate[tid] = __fdividef(1.f, 1.f + __expf(-s));
  }
  __syncthreads();

  // ---- gated messages -> Mf fp32 tile (overwrites Abuf), lightly swizzled ----
  {
    const int o0 = w * 32 + r16, o1 = o0 + 16;
#pragma unroll
    for (int m_ = 0; m_ < 4; ++m_)
#pragma unroll
      for (int r_ = 0; r_ < 4; ++r_) {
        const int er = m_ * 16 + g * 4 + r_;
        const float gg = gate[er];
        Mf[er * 128 + (o0 ^ ((er & 7) << 2))] = acc2[m_][0][r_] * gg;
        Mf[er * 128 + (o1 ^ ((er & 7) << 2))] = acc2[m_][1][r_] * gg;
      }
  }
  __syncthreads();

  // ---- segmented column reduction over sorted srcs; one atomic per run ----
  {
    const int c = tid & 127;
    const int r0 = (tid >> 7) * 32;
    int cur = srcs[r0];
    float a = 0.f;
    for (int row = r0; row < r0 + 32; ++row) {
      const int s = srcs[row];  // wave-uniform
      if (s != cur) {
        atomicAdd(&mi_g[(size_t)cur * DIM + c], a);
        a = 0.f;
        cur = s;
      }
      a += Mf[row * 128 + (c ^ ((row & 7) << 2))];
    }
    atomicAdd(&mi_g[(size_t)cur * DIM + c], a);
  }
}

// ================= node MLP (MFMA, split-K staging) + residual =================
__launch_bounds__(256, 6)
__global__ void node_mfma_kernel(const unsigned short* __restrict__ hbf,
                                 const float* __restrict__ mi_g,
                                 const float* __restrict__ h, const float* __restrict__ stats,
                                 const unsigned short* __restrict__ fw1, const float* __restrict__ fb1,
                                 const unsigned short* __restrict__ fw2, const float* __restrict__ fb2,
                                 float* __restrict__ out) {
  __shared__ unsigned short buf[EB * 128];  // 16 KB

  const int tid = threadIdx.x;
  const int l = tid & 63, w = tid >> 6;
  const int r16 = l & 15, g = l >> 4;
  const int nbase = blockIdx.x * EB;

  const int er_s = tid >> 2, cb_s = (tid & 3) * 4;
  int nstg = nbase + er_s;
  if (nstg >= N_NODES) nstg = N_NODES - 1;

  // ---- phase A: h half ----
  {
    const unsigned short* ps = hbf + (size_t)nstg * DIM;
#pragma unroll
    for (int j = 0; j < 4; ++j) {
      const int c = cb_s + j;
      *(int4*)&buf[er_s * 128 + ((c ^ (er_s & 7)) << 3)] = *(const int4*)(ps + c * 8);
    }
  }
  __syncthreads();

  f32x4 acc[4][2];
#pragma unroll
  for (int m_ = 0; m_ < 4; ++m_)
#pragma unroll
    for (int ni = 0; ni < 2; ++ni) acc[m_][ni] = (f32x4){0.f, 0.f, 0.f, 0.f};

#pragma unroll
  for (int kb = 0; kb < 4; ++kb) {
    short8v a[4], b[2];
#pragma unroll
    for (int m_ = 0; m_ < 4; ++m_) {
      const int er = m_ * 16 + r16;
      a[m_] = *(const short8v*)&buf[er * 128 + (((kb * 4 + g) ^ (er & 7)) << 3)];
    }
#pragma unroll
    for (int ni = 0; ni < 2; ++ni) {
      const int o = w * 32 + ni * 16 + r16;
      b[ni] = *(const short8v*)&fw1[o * 256 + kb * 32 + g * 8];
    }
#pragma unroll
    for (int m_ = 0; m_ < 4; ++m_)
#pragma unroll
      for (int ni = 0; ni < 2; ++ni)
        acc[m_][ni] = __builtin_amdgcn_mfma_f32_16x16x32_bf16(a[m_], b[ni], acc[m_][ni], 0, 0, 0);
  }
  __syncthreads();

  // ---- phase B: m_i half (fp32 -> bf16 on the fly) ----
  {
    const float* pm = mi_g + (size_t)nstg * DIM;
#pragma unroll
    for (int j = 0; j < 4; ++j) {
      const int c = cb_s + j;
      const float4 f0 = *(const float4*)(pm + c * 8);
      const float4 f1 = *(const float4*)(pm + c * 8 + 4);
      int4 v;
      v.x = (int)f2bf(f0.x) | ((int)f2bf(f0.y) << 16);
      v.y = (int)f2bf(f0.z) | ((int)f2bf(f0.w) << 16);
      v.z = (int)f2bf(f1.x) | ((int)f2bf(f1.y) << 16);
      v.w = (int)f2bf(f1.z) | ((int)f2bf(f1.w) << 16);
      *(int4*)&buf[er_s * 128 + ((c ^ (er_s & 7)) << 3)] = v;
    }
  }
  __syncthreads();

#pragma unroll
  for (int kb = 4; kb < 8; ++kb) {
    short8v a[4], b[2];
#pragma unroll
    for (int m_ = 0; m_ < 4; ++m_) {
      const int er = m_ * 16 + r16;
      a[m_] = *(const short8v*)&buf[er * 128 + ((((kb - 4) * 4 + g) ^ (er & 7)) << 3)];
    }
#pragma unroll
    for (int ni = 0; ni < 2; ++ni) {
      const int o = w * 32 + ni * 16 + r16;
      b[ni] = *(const short8v*)&fw1[o * 256 + kb * 32 + g * 8];
    }
#pragma unroll
    for (int m_ = 0; m_ < 4; ++m_)
#pragma unroll
      for (int ni = 0; ni < 2; ++ni)
        acc[m_][ni] = __builtin_amdgcn_mfma_f32_16x16x32_bf16(a[m_], b[ni], acc[m_][ni], 0, 0, 0);
  }
  __syncthreads();

  // ---- bias + SiLU -> A2 (same buffer) ----
  {
    const int o0 = w * 32 + r16, o1 = o0 + 16;
    const float bb0 = fb1[o0], bb1 = fb1[o1];
#pragma unroll
    for (int m_ = 0; m_ < 4; ++m_)
#pragma unroll
      for (int r_ = 0; r_ < 4; ++r_) {
        const int er = m_ * 16 + g * 4 + r_;
        buf[er * 128 + (o0 ^ ((er & 7) << 3))] = f2bf(silu_f(acc[m_][0][r_] + bb0));
        buf[er * 128 + (o1 ^ ((er & 7) << 3))] = f2bf(silu_f(acc[m_][1][r_] + bb1));
      }
  }
  __syncthreads();

  f32x4 acc2[4][2];
#pragma unroll
  for (int m_ = 0; m_ < 4; ++m_)
#pragma unroll
    for (int ni = 0; ni < 2; ++ni) acc2[m_][ni] = (f32x4){0.f, 0.f, 0.f, 0.f};

#pragma unroll
  for (int kb = 0; kb < 4; ++kb) {
    short8v a[4], b[2];
    const int k0 = kb * 32 + g * 8;
#pragma unroll
    for (int m_ = 0; m_ < 4; ++m_) {
      const int er = m_ * 16 + r16;
      a[m_] = *(const short8v*)&buf[er * 128 + (k0 ^ ((er & 7) << 3))];
    }
#pragma unroll
    for (int ni = 0; ni < 2; ++ni) {
      const int o = w * 32 + ni * 16 + r16;
      b[ni] = *(const short8v*)&fw2[o * 128 + k0];
    }
#pragma unroll
    for (int m_ = 0; m_ < 4; ++m_)
#pragma unroll
      for (int ni = 0; ni < 2; ++ni)
        acc2[m_][ni] = __builtin_amdgcn_mfma_f32_16x16x32_bf16(a[m_], b[ni], acc2[m_][ni], 0, 0, 0);
  }

  // epilogue: out = BN(h) + update
#pragma unroll
  for (int ni = 0; ni < 2; ++ni) {
    const int o = w * 32 + ni * 16 + r16;
    const float bb = fb2[o];
    const float sc = stats[2 * DIM + o];
    const float sh = stats[3 * DIM + o];
#pragma unroll
    for (int m_ = 0; m_ < 4; ++m_)
#pragma unroll
      for (int r_ = 0; r_ < 4; ++r_) {
        const int n = nbase + m_ * 16 + g * 4 + r_;
        if (n < N_NODES) {
          const float hv = h[(size_t)n * DIM + o];
          out[(size_t)n * DIM + o] = hv * sc + sh + acc2[m_][ni][r_] + bb;
        }
      }
  }
}

extern "C" void kernel_launch(void* const* d_in, const int* in_sizes, int n_in, void* d_out,
                              int out_size, void* d_ws, size_t ws_size, hipStream_t stream) {
  const float* h = (const float*)d_in[0];
  const float* x = (const float*)d_in[1];
  const int* e = (const int*)d_in[2];
  const float* bn_gamma = (const float*)d_in[3];
  const float* bn_beta = (const float*)d_in[4];
  const float* fe_w1 = (const float*)d_in[5];
  const float* fe_b1 = (const float*)d_in[6];
  const float* fe_w2 = (const float*)d_in[7];
  const float* fe_b2 = (const float*)d_in[8];
  const float* finf_w = (const float*)d_in[9];
  const float* finf_b = (const float*)d_in[10];
  const float* fh_w1 = (const float*)d_in[11];
  const float* fh_b1 = (const float*)d_in[12];
  const float* fh_w2 = (const float*)d_in[13];
  const float* fh_b2 = (const float*)d_in[14];

  char* wp = (char*)d_ws;
  auto alloc = [&](size_t bytes) -> char* {
    char* p = wp;
    wp += (bytes + 255) & ~(size_t)255;
    return p;
  };
  float* stats = (float*)alloc(512 * sizeof(float));        // 2048 B (256-aligned)
  int* cnt = (int*)alloc((size_t)N_NODES * 4);              // adjacent to stats for one memset
  unsigned short* hbf = (unsigned short*)alloc((size_t)N_NODES * DIM * 2);
  unsigned short* w1bf = (unsigned short*)alloc(128 * 256 * 2);
  float* w1col = (float*)alloc(128 * 4);
  unsigned short* w2bf = (unsigned short*)alloc(128 * 128 * 2);
  unsigned short* fw1bf = (unsigned short*)alloc(128 * 256 * 2);
  unsigned short* fw2bf = (unsigned short*)alloc(128 * 128 * 2);
  int* cursor = (int*)alloc((size_t)N_NODES * 4);
  int* bsum = (int*)alloc((size_t)SCAN_B * 4);
  int* srcS = (int*)alloc((size_t)N_EDGES * 4);
  int* dstS = (int*)alloc((size_t)N_EDGES * 4);
  float* distS = (float*)alloc((size_t)N_EDGES * 4);
  float* mi_g = (float*)alloc((size_t)N_NODES * DIM * 4);

  float* out = (float*)d_out;
  float* out_e = out + (size_t)N_NODES * DIM;

  // one memset covers stats (2048 B) + cnt (200000 B), laid out contiguously
  hipMemsetAsync(stats, 0, 2048 + (size_t)N_NODES * 4, stream);

  k1_fused_kernel<<<BN_B + HIST_B + ECOPY_B + PREP_B, 256, 0, stream>>>(
      h, e, fe_w1, fe_w2, fh_w1, fh_w2, stats, cnt, out_e, w1bf, w1col, w2bf, fw1bf, fw2bf);
  k2_fused_kernel<<<SCAN_B + 1, 256, 0, stream>>>(cnt, bsum, stats, bn_gamma, bn_beta);
  scanB_kernel<<<1, 256, 0, stream>>>(bsum);
  k3_fused_kernel<<<SCAN_B + APPLY_B + MIZ_B, 256, 0, stream>>>(cnt, bsum, cursor, h, stats, hbf,
                                                                mi_g);
  sort_scatter_kernel<<<(N_EDGES + 255) / 256, 256, 0, stream>>>(e, x, cursor, srcS, dstS, distS);
  edge_mfma_kernel<<<N_EDGES / EB, 256, 0, stream>>>(hbf, srcS, dstS, distS, w1bf, w1col, fe_b1,
                                                     w2bf, fe_b2, finf_w, finf_b, mi_g);
  node_mfma_kernel<<<(N_NODES + EB - 1) / EB, 256, 0, stream>>>(hbf, mi_g, h, stats, fw1bf, fh_b1,
                                                                fw2bf, fh_b2, out);
}